// Round 1
// baseline (5134.886 us; speedup 1.0000x reference)
//
#include <hip/hip_runtime.h>
#include <hip/hip_bf16.h>

// LSTMNet: B=512, T=1024, IN=32, H=128 (gates G=512), 2 layers, head 128->256->32 (CELU).
// Round 0: all-fp32 correctness baseline.
//   - T chunked into TC slices so xg (512*TC*512 f32) + h0 chunk stay L3-resident.
//   - lstm_scan: 256 blocks x 512 threads, 2 batch rows/block. Thread g owns weight
//     row Whh[g][0:128] in registers (128 VGPR); h broadcast via LDS float4 reads
//     (same-address broadcast = conflict-free). Gate order i,f,g,o per jnp.split.
//   - gemm_in: 64x64 tile, BK=64 (LDS 2*64*68*4 = 34.8 KB), strided 4x4 microtile
//     (cols tx+16j, rows ty+16i) -> LDS read stride 68 floats == 4 banks -> <=2-way.

#define DEV __device__ __forceinline__

DEV float sigm(float x) { return 1.f / (1.f + __expf(-x)); }
DEV float tanhfast(float x) { float e = __expf(2.f * x); return (e - 1.f) / (e + 1.f); }
DEV float celu1(float x) { return x > 0.f ? x : (__expf(x) - 1.f); }

// C[r][g] = sum_k A_row(r)[k] * W[g][k] + bA[g] + bB[g];  r in [0, 512*TC), g in [0,512)
// XMAP: A = x (B,1024,32), row r -> (b = r/TC, t = t0 + r%TC). else A = contiguous [r][K].
template<int K, bool XMAP>
__global__ __launch_bounds__(256, 2)
void gemm_in(const float* __restrict__ A, const float* __restrict__ W,
             const float* __restrict__ bA, const float* __restrict__ bB,
             float* __restrict__ C, int t0, int TC)
{
    constexpr int BM = 64, BN = 64;
    constexpr int BK = (K < 64) ? K : 64;
    constexpr int RW = BK + 4;                 // stride 68 (or 36): 4-bank step, <=2-way
    __shared__ float As[BM * RW];
    __shared__ float Ws[BN * RW];

    const int tid = threadIdx.x;
    const int r0 = blockIdx.x * BM;
    const int g0 = blockIdx.y * BN;
    const int tx = tid & 15, ty = tid >> 4;

    float acc[4][4];
#pragma unroll
    for (int i = 0; i < 4; i++)
#pragma unroll
        for (int j = 0; j < 4; j++) acc[i][j] = 0.f;

    for (int kb = 0; kb < K; kb += BK) {
        constexpr int NF4 = BM * (BK / 4) / 256;   // float4 loads per thread per tile
#pragma unroll
        for (int e = 0; e < NF4; e++) {
            int idx = tid + e * 256;
            int row = idx / (BK / 4);
            int kk  = (idx % (BK / 4)) * 4;
            // A tile
            int r = r0 + row;
            size_t src;
            if (XMAP) {
                int b = r / TC, tt = r - b * TC;
                src = ((size_t)b * 1024 + (size_t)(t0 + tt)) * 32 + (size_t)(kb + kk);
            } else {
                src = (size_t)r * K + (size_t)(kb + kk);
            }
            float4 av = *(const float4*)(A + src);
            *(float4*)&As[row * RW + kk] = av;
            // W tile
            float4 wv = *(const float4*)(W + (size_t)(g0 + row) * K + (size_t)(kb + kk));
            *(float4*)&Ws[row * RW + kk] = wv;
        }
        __syncthreads();

#pragma unroll 2
        for (int k = 0; k < BK; k += 4) {
            float4 a[4], w[4];
#pragma unroll
            for (int i = 0; i < 4; i++) a[i] = *(const float4*)&As[(ty + i * 16) * RW + k];
#pragma unroll
            for (int j = 0; j < 4; j++) w[j] = *(const float4*)&Ws[(tx + j * 16) * RW + k];
#pragma unroll
            for (int i = 0; i < 4; i++)
#pragma unroll
                for (int j = 0; j < 4; j++)
                    acc[i][j] += a[i].x * w[j].x + a[i].y * w[j].y
                               + a[i].z * w[j].z + a[i].w * w[j].w;
        }
        __syncthreads();
    }

#pragma unroll
    for (int j = 0; j < 4; j++) {
        int g = g0 + tx + j * 16;
        float bias = bA[g] + bB[g];
#pragma unroll
        for (int i = 0; i < 4; i++) {
            int r = r0 + ty + i * 16;
            C[(size_t)r * 512 + g] = acc[i][j] + bias;
        }
    }
}

// One block per 2 batch rows; thread g in [0,512) owns gate column g (weight row in regs).
// Update phase: threads 0..255 own (b = g>>7, k = g&127), keep c in a register.
template<int WRITE_H>
__global__ __launch_bounds__(512, 2)
void lstm_scan(const float* __restrict__ xg, const float* __restrict__ Whh,
               float* __restrict__ hs, float* __restrict__ cs,
               float* __restrict__ hout, int TC)
{
    __shared__ float h_lds[2][128];
    __shared__ float pre[2][512];
    const int g = threadIdx.x;
    const int b0 = blockIdx.x * 2;

    // weight row Whh[g][0:128] -> 128 VGPRs (static indexing, fully unrolled)
    float w[128];
    {
        const float4* wp = (const float4*)(Whh + (size_t)g * 128);
#pragma unroll
        for (int q = 0; q < 32; q++) {
            float4 v = wp[q];
            w[q * 4 + 0] = v.x; w[q * 4 + 1] = v.y;
            w[q * 4 + 2] = v.z; w[q * 4 + 3] = v.w;
        }
    }
    float c_reg = 0.f;
    if (g < 256) {
        int b = g >> 7, k = g & 127;
        h_lds[b][k] = hs[(size_t)(b0 + b) * 128 + k];
        c_reg       = cs[(size_t)(b0 + b) * 128 + k];
    }
    __syncthreads();

    const size_t xrow0 = (size_t)b0 * TC * 512;
    const size_t xrow1 = (size_t)(b0 + 1) * TC * 512;

    for (int tt = 0; tt < TC; tt++) {
        // issue xg loads first; recurrence accumulates separately so the MAC loop hides latency
        float x0 = xg[xrow0 + (size_t)tt * 512 + g];
        float x1 = xg[xrow1 + (size_t)tt * 512 + g];
        float r0a = 0.f, r0b = 0.f, r1a = 0.f, r1b = 0.f;
        const float4* h0p = (const float4*)h_lds[0];
        const float4* h1p = (const float4*)h_lds[1];
#pragma unroll
        for (int q = 0; q < 32; q++) {
            float4 ha = h0p[q];       // all-lane broadcast reads: conflict-free
            float4 hb = h1p[q];
            float s0 = ha.x * w[q*4] + ha.y * w[q*4+1] + ha.z * w[q*4+2] + ha.w * w[q*4+3];
            float s1 = hb.x * w[q*4] + hb.y * w[q*4+1] + hb.z * w[q*4+2] + hb.w * w[q*4+3];
            if (q & 1) { r0b += s0; r1b += s1; } else { r0a += s0; r1a += s1; }
        }
        pre[0][g] = x0 + (r0a + r0b);
        pre[1][g] = x1 + (r1a + r1b);
        __syncthreads();
        if (g < 256) {
            int b = g >> 7, k = g & 127;
            float pi = pre[b][k];
            float pf = pre[b][k + 128];
            float pg = pre[b][k + 256];
            float po = pre[b][k + 384];
            float iv = sigm(pi), fv = sigm(pf), gv = tanhfast(pg), ov = sigm(po);
            c_reg = fv * c_reg + iv * gv;
            float hv = ov * tanhfast(c_reg);
            h_lds[b][k] = hv;
            if (WRITE_H)
                hout[((size_t)(b0 + b) * TC + tt) * 128 + k] = hv;
        }
        __syncthreads();
    }
    if (g < 256) {
        int b = g >> 7, k = g & 127;
        hs[(size_t)(b0 + b) * 128 + k] = h_lds[b][k];
        cs[(size_t)(b0 + b) * 128 + k] = c_reg;
    }
}

// y1 = celu(last @ W1^T + b1)  (256);  y = celu(y1 @ W2^T + b2)  (32). One block per batch row.
__global__ __launch_bounds__(256, 2)
void head_k(const float* __restrict__ h1s, const float* __restrict__ W1,
            const float* __restrict__ b1, const float* __restrict__ W2,
            const float* __restrict__ b2, float* __restrict__ out)
{
    __shared__ float hrow[128];
    __shared__ float y1[256];
    const int b = blockIdx.x;
    const int tid = threadIdx.x;
    if (tid < 128) hrow[tid] = h1s[(size_t)b * 128 + tid];
    __syncthreads();
    {
        float acc = b1[tid];
        const float4* wp = (const float4*)(W1 + (size_t)tid * 128);
        const float4* hp = (const float4*)hrow;
#pragma unroll 8
        for (int q = 0; q < 32; q++) {
            float4 wv = wp[q]; float4 hv = hp[q];
            acc += wv.x * hv.x + wv.y * hv.y + wv.z * hv.z + wv.w * hv.w;
        }
        y1[tid] = celu1(acc);
    }
    __syncthreads();
    if (tid < 32) {
        float acc = b2[tid];
        const float4* wp = (const float4*)(W2 + (size_t)tid * 256);
        const float4* yp = (const float4*)y1;
#pragma unroll 8
        for (int q = 0; q < 64; q++) {
            float4 wv = wp[q]; float4 yv = yp[q];
            acc += wv.x * yv.x + wv.y * yv.y + wv.z * yv.z + wv.w * yv.w;
        }
        out[(size_t)b * 32 + tid] = celu1(acc);
    }
}

extern "C" void kernel_launch(void* const* d_in, const int* in_sizes, int n_in,
                              void* d_out, int out_size, void* d_ws, size_t ws_size,
                              hipStream_t stream)
{
    const float* x    = (const float*)d_in[0];
    const float* Wih0 = (const float*)d_in[1];
    const float* Whh0 = (const float*)d_in[2];
    const float* bih0 = (const float*)d_in[3];
    const float* bhh0 = (const float*)d_in[4];
    const float* Wih1 = (const float*)d_in[5];
    const float* Whh1 = (const float*)d_in[6];
    const float* bih1 = (const float*)d_in[7];
    const float* bhh1 = (const float*)d_in[8];
    const float* W1   = (const float*)d_in[9];
    const float* b1   = (const float*)d_in[10];
    const float* W2   = (const float*)d_in[11];
    const float* b2   = (const float*)d_in[12];
    float* out = (float*)d_out;

    // pick largest TC (divides 1024) whose scratch fits ws: xg + h0 chunk + 4 state arrays
    int TC = 128;
    while (TC > 8) {
        size_t need = (size_t)TC * (512ull * 512 + 512ull * 128) * 4 + 4ull * 512 * 128 * 4;
        if (need <= ws_size) break;
        TC >>= 1;
    }

    float* xg  = (float*)d_ws;                       // 512*TC*512 f32
    float* h0c = xg + (size_t)512 * TC * 512;        // 512*TC*128 f32
    float* st  = h0c + (size_t)512 * TC * 128;       // 4 x 512*128 f32 states
    float* h0s = st;
    float* c0s = st + 512 * 128;
    float* h1s = st + 2 * 512 * 128;
    float* c1s = st + 3 * 512 * 128;

    hipMemsetAsync(st, 0, (size_t)4 * 512 * 128 * 4, stream);          // h,c = 0
    hipMemsetAsync(out + 16384, 0, (size_t)131072 * 4, stream);        // hidden_init = 0

    const int NC = 1024 / TC;
    dim3 ggrid((unsigned)(512 * TC / 64), 8);
    for (int c = 0; c < NC; c++) {
        int t0 = c * TC;
        gemm_in<32,  true ><<<ggrid, 256, 0, stream>>>(x,   Wih0, bih0, bhh0, xg, t0, TC);
        lstm_scan<1><<<256, 512, 0, stream>>>(xg, Whh0, h0s, c0s, h0c, TC);
        gemm_in<128, false><<<ggrid, 256, 0, stream>>>(h0c, Wih1, bih1, bhh1, xg, t0, TC);
        lstm_scan<0><<<256, 512, 0, stream>>>(xg, Whh1, h1s, c1s, nullptr, TC);
    }
    head_k<<<512, 256, 0, stream>>>(h1s, W1, b1, W2, b2, out);
}

// Round 2
// 4911.319 us; speedup vs baseline: 1.0455x; 1.0455x over previous
//
#include <hip/hip_runtime.h>
#include <hip/hip_bf16.h>

// LSTMNet: B=512, T=1024, IN=32, H=128 (gates G=512), 2 layers, head 128->256->32 (CELU).
// Round 2: fix lstm_scan — pin Whh rows in VGPRs (round-1 showed VGPR=84 => weights were
// re-loaded from memory every step), and halve LDS broadcast traffic via k-split pairs:
// thread t owns gates {t&~1, t|1} over k-half (t&1)*64; each h float4 feeds 2 gates;
// halves combined with 2 same-wave __shfl_xor. GEMMs unchanged (next round: MFMA).

#define DEV __device__ __forceinline__

typedef float f32x4 __attribute__((ext_vector_type(4)));

DEV float sigm(float x) { return 1.f / (1.f + __expf(-x)); }
DEV float tanhfast(float x) { float e = __expf(2.f * x); return (e - 1.f) / (e + 1.f); }
DEV float celu1(float x) { return x > 0.f ? x : (__expf(x) - 1.f); }

DEV float dot4(f32x4 a, f32x4 b, float acc) {
    acc = fmaf(a.x, b.x, acc);
    acc = fmaf(a.y, b.y, acc);
    acc = fmaf(a.z, b.z, acc);
    acc = fmaf(a.w, b.w, acc);
    return acc;
}

// C[r][g] = sum_k A_row(r)[k] * W[g][k] + bA[g] + bB[g];  r in [0, 512*TC), g in [0,512)
// XMAP: A = x (B,1024,32), row r -> (b = r/TC, t = t0 + r%TC). else A = contiguous [r][K].
template<int K, bool XMAP>
__global__ __launch_bounds__(256, 2)
void gemm_in(const float* __restrict__ A, const float* __restrict__ W,
             const float* __restrict__ bA, const float* __restrict__ bB,
             float* __restrict__ C, int t0, int TC)
{
    constexpr int BM = 64, BN = 64;
    constexpr int BK = (K < 64) ? K : 64;
    constexpr int RW = BK + 4;                 // stride 68 (or 36): 4-bank step, <=2-way
    __shared__ float As[BM * RW];
    __shared__ float Ws[BN * RW];

    const int tid = threadIdx.x;
    const int r0 = blockIdx.x * BM;
    const int g0 = blockIdx.y * BN;
    const int tx = tid & 15, ty = tid >> 4;

    float acc[4][4];
#pragma unroll
    for (int i = 0; i < 4; i++)
#pragma unroll
        for (int j = 0; j < 4; j++) acc[i][j] = 0.f;

    for (int kb = 0; kb < K; kb += BK) {
        constexpr int NF4 = BM * (BK / 4) / 256;   // float4 loads per thread per tile
#pragma unroll
        for (int e = 0; e < NF4; e++) {
            int idx = tid + e * 256;
            int row = idx / (BK / 4);
            int kk  = (idx % (BK / 4)) * 4;
            int r = r0 + row;
            size_t src;
            if (XMAP) {
                int b = r / TC, tt = r - b * TC;
                src = ((size_t)b * 1024 + (size_t)(t0 + tt)) * 32 + (size_t)(kb + kk);
            } else {
                src = (size_t)r * K + (size_t)(kb + kk);
            }
            float4 av = *(const float4*)(A + src);
            *(float4*)&As[row * RW + kk] = av;
            float4 wv = *(const float4*)(W + (size_t)(g0 + row) * K + (size_t)(kb + kk));
            *(float4*)&Ws[row * RW + kk] = wv;
        }
        __syncthreads();

#pragma unroll 2
        for (int k = 0; k < BK; k += 4) {
            float4 a[4], w[4];
#pragma unroll
            for (int i = 0; i < 4; i++) a[i] = *(const float4*)&As[(ty + i * 16) * RW + k];
#pragma unroll
            for (int j = 0; j < 4; j++) w[j] = *(const float4*)&Ws[(tx + j * 16) * RW + k];
#pragma unroll
            for (int i = 0; i < 4; i++)
#pragma unroll
                for (int j = 0; j < 4; j++)
                    acc[i][j] += a[i].x * w[j].x + a[i].y * w[j].y
                               + a[i].z * w[j].z + a[i].w * w[j].w;
        }
        __syncthreads();
    }

#pragma unroll
    for (int j = 0; j < 4; j++) {
        int g = g0 + tx + j * 16;
        float bias = bA[g] + bB[g];
#pragma unroll
        for (int i = 0; i < 4; i++) {
            int r = r0 + ty + i * 16;
            C[(size_t)r * 512 + g] = acc[i][j] + bias;
        }
    }
}

#define PIN8(a) asm volatile("" : "+v"(a[0]), "+v"(a[1]), "+v"(a[2]), "+v"(a[3]), \
                                  "+v"(a[4]), "+v"(a[5]), "+v"(a[6]), "+v"(a[7]))

// One block per 2 batch rows; 512 threads. Thread t owns gates gA=t&~1, gB=t|1 over
// k-half kh=(t&1)*64 (weights: 32 f32x4 = 128 VGPR, pinned). Full k-sums for gate t
// are completed with one __shfl_xor(.,1) per row. Update phase: threads 0..255 own
// (b = t>>7, k = t&127), keep c in a register.
template<int WRITE_H>
__global__ __launch_bounds__(512, 2)
void lstm_scan(const float* __restrict__ xg, const float* __restrict__ Whh,
               float* __restrict__ hs, float* __restrict__ cs,
               float* __restrict__ hout, int TC)
{
    __shared__ float h_lds[2][128];
    __shared__ float pre[2][512];
    const int t = threadIdx.x;
    const int b0 = blockIdx.x * 2;
    const int gA = t & ~1;
    const int kh = (t & 1) * 64;

    // weights: rows gA and gA+1, cols [kh, kh+64) -> 32 f32x4, pinned into VGPRs
    f32x4 wa[16], wb[16];
    {
        const f32x4* pA = (const f32x4*)(Whh + (size_t)gA * 128 + kh);
        const f32x4* pB = (const f32x4*)(Whh + (size_t)(gA + 1) * 128 + kh);
#pragma unroll
        for (int q = 0; q < 16; q++) { wa[q] = pA[q]; wb[q] = pB[q]; }
    }
    PIN8(wa); PIN8((wa + 8)); PIN8(wb); PIN8((wb + 8));

    float c_reg = 0.f;
    if (t < 256) {
        int b = t >> 7, k = t & 127;
        h_lds[b][k] = hs[(size_t)(b0 + b) * 128 + k];
        c_reg       = cs[(size_t)(b0 + b) * 128 + k];
    }
    __syncthreads();

    const size_t xrow0 = (size_t)b0 * TC * 512;
    const size_t xrow1 = (size_t)(b0 + 1) * TC * 512;

    for (int tt = 0; tt < TC; tt++) {
        float x0 = xg[xrow0 + (size_t)tt * 512 + t];
        float x1 = xg[xrow1 + (size_t)tt * 512 + t];

        float pa0 = 0.f, pa1 = 0.f, pb0 = 0.f, pb1 = 0.f;
        const f32x4* h0p = (const f32x4*)(&h_lds[0][kh]);
        const f32x4* h1p = (const f32x4*)(&h_lds[1][kh]);
#pragma unroll
        for (int q = 0; q < 16; q++) {
            f32x4 h0 = h0p[q];           // 2-address broadcast across wave: conflict-free
            f32x4 h1 = h1p[q];
            pa0 = dot4(wa[q], h0, pa0);
            pa1 = dot4(wa[q], h1, pa1);
            pb0 = dot4(wb[q], h0, pb0);
            pb1 = dot4(wb[q], h1, pb1);
        }
        // complete k-sums: send partner the partial for ITS gate, keep mine
        float send0 = (t & 1) ? pa0 : pb0;
        float send1 = (t & 1) ? pa1 : pb1;
        float mine0 = (t & 1) ? pb0 : pa0;
        float mine1 = (t & 1) ? pb1 : pa1;
        float recv0 = __shfl_xor(send0, 1);
        float recv1 = __shfl_xor(send1, 1);
        pre[0][t] = x0 + mine0 + recv0;
        pre[1][t] = x1 + mine1 + recv1;
        __syncthreads();

        if (t < 256) {
            int b = t >> 7, k = t & 127;
            float pi = pre[b][k];
            float pf = pre[b][k + 128];
            float pg = pre[b][k + 256];
            float po = pre[b][k + 384];
            float iv = sigm(pi), fv = sigm(pf), gv = tanhfast(pg), ov = sigm(po);
            c_reg = fv * c_reg + iv * gv;
            float hv = ov * tanhfast(c_reg);
            h_lds[b][k] = hv;
            if (WRITE_H)
                hout[((size_t)(b0 + b) * TC + tt) * 128 + k] = hv;
        }
        __syncthreads();
    }
    if (t < 256) {
        int b = t >> 7, k = t & 127;
        hs[(size_t)(b0 + b) * 128 + k] = h_lds[b][k];
        cs[(size_t)(b0 + b) * 128 + k] = c_reg;
    }
}

// y1 = celu(last @ W1^T + b1)  (256);  y = celu(y1 @ W2^T + b2)  (32). One block per batch row.
__global__ __launch_bounds__(256, 2)
void head_k(const float* __restrict__ h1s, const float* __restrict__ W1,
            const float* __restrict__ b1, const float* __restrict__ W2,
            const float* __restrict__ b2, float* __restrict__ out)
{
    __shared__ float hrow[128];
    __shared__ float y1[256];
    const int b = blockIdx.x;
    const int tid = threadIdx.x;
    if (tid < 128) hrow[tid] = h1s[(size_t)b * 128 + tid];
    __syncthreads();
    {
        float acc = b1[tid];
        const float4* wp = (const float4*)(W1 + (size_t)tid * 128);
        const float4* hp = (const float4*)hrow;
#pragma unroll 8
        for (int q = 0; q < 32; q++) {
            float4 wv = wp[q]; float4 hv = hp[q];
            acc += wv.x * hv.x + wv.y * hv.y + wv.z * hv.z + wv.w * hv.w;
        }
        y1[tid] = celu1(acc);
    }
    __syncthreads();
    if (tid < 32) {
        float acc = b2[tid];
        const float4* wp = (const float4*)(W2 + (size_t)tid * 256);
        const float4* yp = (const float4*)y1;
#pragma unroll 8
        for (int q = 0; q < 64; q++) {
            float4 wv = wp[q]; float4 yv = yp[q];
            acc += wv.x * yv.x + wv.y * yv.y + wv.z * yv.z + wv.w * yv.w;
        }
        out[(size_t)b * 32 + tid] = celu1(acc);
    }
}

extern "C" void kernel_launch(void* const* d_in, const int* in_sizes, int n_in,
                              void* d_out, int out_size, void* d_ws, size_t ws_size,
                              hipStream_t stream)
{
    const float* x    = (const float*)d_in[0];
    const float* Wih0 = (const float*)d_in[1];
    const float* Whh0 = (const float*)d_in[2];
    const float* bih0 = (const float*)d_in[3];
    const float* bhh0 = (const float*)d_in[4];
    const float* Wih1 = (const float*)d_in[5];
    const float* Whh1 = (const float*)d_in[6];
    const float* bih1 = (const float*)d_in[7];
    const float* bhh1 = (const float*)d_in[8];
    const float* W1   = (const float*)d_in[9];
    const float* b1   = (const float*)d_in[10];
    const float* W2   = (const float*)d_in[11];
    const float* b2   = (const float*)d_in[12];
    float* out = (float*)d_out;

    // pick largest TC (divides 1024) whose scratch fits ws: xg + h0 chunk + 4 state arrays
    int TC = 128;
    while (TC > 8) {
        size_t need = (size_t)TC * (512ull * 512 + 512ull * 128) * 4 + 4ull * 512 * 128 * 4;
        if (need <= ws_size) break;
        TC >>= 1;
    }

    float* xg  = (float*)d_ws;                       // 512*TC*512 f32
    float* h0c = xg + (size_t)512 * TC * 512;        // 512*TC*128 f32
    float* st  = h0c + (size_t)512 * TC * 128;       // 4 x 512*128 f32 states
    float* h0s = st;
    float* c0s = st + 512 * 128;
    float* h1s = st + 2 * 512 * 128;
    float* c1s = st + 3 * 512 * 128;

    hipMemsetAsync(st, 0, (size_t)4 * 512 * 128 * 4, stream);          // h,c = 0
    hipMemsetAsync(out + 16384, 0, (size_t)131072 * 4, stream);        // hidden_init = 0

    const int NC = 1024 / TC;
    dim3 ggrid((unsigned)(512 * TC / 64), 8);
    for (int c = 0; c < NC; c++) {
        int t0 = c * TC;
        gemm_in<32,  true ><<<ggrid, 256, 0, stream>>>(x,   Wih0, bih0, bhh0, xg, t0, TC);
        lstm_scan<1><<<256, 512, 0, stream>>>(xg, Whh0, h0s, c0s, h0c, TC);
        gemm_in<128, false><<<ggrid, 256, 0, stream>>>(h0c, Wih1, bih1, bhh1, xg, t0, TC);
        lstm_scan<0><<<256, 512, 0, stream>>>(xg, Whh1, h1s, c1s, nullptr, TC);
    }
    head_k<<<512, 256, 0, stream>>>(h1s, W1, b1, W2, b2, out);
}

// Round 3
// 3383.540 us; speedup vs baseline: 1.5176x; 1.4515x over previous
//
#include <hip/hip_runtime.h>
#include <hip/hip_bf16.h>

// LSTMNet: B=512, T=1024, IN=32, H=128 (gates G=512), 2 layers, head 128->256->32 (CELU).
// Round 2: MFMA scan. Per block: 4 batch rows, full 512 gates, K=128 via
// mfma_f32_16x16x32_bf16 (bf16 h & Whh, fp32 accum/c/xg). Wave w owns gate channels
// w*16..w*16+15 across all 4 gate types (N-tiles q*128+w*16). Weights = 16 bf16x8
// B-fragments = 64 VGPR/lane, loaded once. h kept bf16 in LDS, XOR-swizzled
// (^ (row&7)<<4) so A-frag ds_read_b128 is 2-way (free). Preacts redistributed via
// LDS so each of 512 threads updates exactly 1 (batch,channel) gate-quad
// (8 transcendentals/thread/step). 2 barriers/step. GEMMs still fp32 (next round).

#define DEV __device__ __forceinline__

typedef float f32x4 __attribute__((ext_vector_type(4)));
typedef short bf16x8 __attribute__((ext_vector_type(8)));

DEV float sigm(float x) { return 1.f / (1.f + __expf(-x)); }
DEV float tanhfast(float x) { float e = __expf(2.f * x); return (e - 1.f) / (e + 1.f); }
DEV float celu1(float x) { return x > 0.f ? x : (__expf(x) - 1.f); }

DEV short f2bf(float f) {
    __hip_bfloat16 h = __float2bfloat16(f);   // RNE
    return *reinterpret_cast<short*>(&h);
}

// ---------------- input-projection GEMM (fp32, unchanged from round 1) --------------
template<int K, bool XMAP>
__global__ __launch_bounds__(256, 2)
void gemm_in(const float* __restrict__ A, const float* __restrict__ W,
             const float* __restrict__ bA, const float* __restrict__ bB,
             float* __restrict__ C, int t0, int TC)
{
    constexpr int BM = 64, BN = 64;
    constexpr int BK = (K < 64) ? K : 64;
    constexpr int RW = BK + 4;
    __shared__ float As[BM * RW];
    __shared__ float Ws[BN * RW];

    const int tid = threadIdx.x;
    const int r0 = blockIdx.x * BM;
    const int g0 = blockIdx.y * BN;
    const int tx = tid & 15, ty = tid >> 4;

    float acc[4][4];
#pragma unroll
    for (int i = 0; i < 4; i++)
#pragma unroll
        for (int j = 0; j < 4; j++) acc[i][j] = 0.f;

    for (int kb = 0; kb < K; kb += BK) {
        constexpr int NF4 = BM * (BK / 4) / 256;
#pragma unroll
        for (int e = 0; e < NF4; e++) {
            int idx = tid + e * 256;
            int row = idx / (BK / 4);
            int kk  = (idx % (BK / 4)) * 4;
            int r = r0 + row;
            size_t src;
            if (XMAP) {
                int b = r / TC, tt = r - b * TC;
                src = ((size_t)b * 1024 + (size_t)(t0 + tt)) * 32 + (size_t)(kb + kk);
            } else {
                src = (size_t)r * K + (size_t)(kb + kk);
            }
            float4 av = *(const float4*)(A + src);
            *(float4*)&As[row * RW + kk] = av;
            float4 wv = *(const float4*)(W + (size_t)(g0 + row) * K + (size_t)(kb + kk));
            *(float4*)&Ws[row * RW + kk] = wv;
        }
        __syncthreads();

#pragma unroll 2
        for (int k = 0; k < BK; k += 4) {
            float4 a[4], w[4];
#pragma unroll
            for (int i = 0; i < 4; i++) a[i] = *(const float4*)&As[(ty + i * 16) * RW + k];
#pragma unroll
            for (int j = 0; j < 4; j++) w[j] = *(const float4*)&Ws[(tx + j * 16) * RW + k];
#pragma unroll
            for (int i = 0; i < 4; i++)
#pragma unroll
                for (int j = 0; j < 4; j++)
                    acc[i][j] += a[i].x * w[j].x + a[i].y * w[j].y
                               + a[i].z * w[j].z + a[i].w * w[j].w;
        }
        __syncthreads();
    }

#pragma unroll
    for (int j = 0; j < 4; j++) {
        int g = g0 + tx + j * 16;
        float bias = bA[g] + bB[g];
#pragma unroll
        for (int i = 0; i < 4; i++) {
            int r = r0 + ty + i * 16;
            C[(size_t)r * 512 + g] = acc[i][j] + bias;
        }
    }
}

// ---------------- MFMA LSTM scan ----------------------------------------------------
// grid = 128 blocks (4 batch rows each), 512 threads (8 waves).
// MFMA: D[m][n]: m = (lane>>4)*4+reg (batches 0-3 real), n = lane&15 (channel in tile).
// A-frag: h[m=lane&15][k=(lane>>4)*8+j] bf16 (rows 4-15 zeroed once).
// B-frag: Whh[n0+(lane&15)][k=(lane>>4)*8+j] bf16, n0 = q*128 + w*16.
template<int WRITE_H>
__global__ __launch_bounds__(512, 2)
void lstm_scan(const float* __restrict__ xg, const float* __restrict__ Whh,
               float* __restrict__ hs, float* __restrict__ cs,
               float* __restrict__ hout, int TC)
{
    __shared__ short h_lds[16 * 128];          // bf16 bits, byte-swizzled ^((m&7)<<4)
    __shared__ float pre[4 * 4 * 128];         // [q][m][ch]

    const int t    = threadIdx.x;
    const int lane = t & 63;
    const int w    = t >> 6;                   // wave 0..7
    const int b0   = blockIdx.x * 4;
    const int um   = t >> 7;                   // update: batch row 0..3
    const int uch  = t & 127;                  // update: channel 0..127

    // ---- Whh -> bf16 B-fragments (once) ----
    bf16x8 Wf[4][4];
    {
        const int row_base = w * 16 + (lane & 15);
        const int kbase    = (lane >> 4) * 8;
#pragma unroll
        for (int q = 0; q < 4; q++) {
            const float* wr = Whh + (size_t)(q * 128 + row_base) * 128;
#pragma unroll
            for (int kt = 0; kt < 4; kt++) {
                const float* p = wr + kt * 32 + kbase;
                bf16x8 v;
#pragma unroll
                for (int j = 0; j < 8; j++) v[j] = f2bf(p[j]);
                Wf[q][kt] = v;
            }
        }
    }
    asm volatile("" : "+v"(Wf[0][0]), "+v"(Wf[0][1]), "+v"(Wf[0][2]), "+v"(Wf[0][3]),
                      "+v"(Wf[1][0]), "+v"(Wf[1][1]), "+v"(Wf[1][2]), "+v"(Wf[1][3]),
                      "+v"(Wf[2][0]), "+v"(Wf[2][1]), "+v"(Wf[2][2]), "+v"(Wf[2][3]),
                      "+v"(Wf[3][0]), "+v"(Wf[3][1]), "+v"(Wf[3][2]), "+v"(Wf[3][3]));

    // ---- state init ----
    float c_reg  = cs[(size_t)(b0 + um) * 128 + uch];
    float h_keep = hs[(size_t)(b0 + um) * 128 + uch];
    *(short*)((char*)h_lds + um * 256 + ((uch * 2) ^ (um << 4))) = f2bf(h_keep);
    if (t < 384)   // zero rows 4..15 (A-tile padding)
        *(unsigned long long*)((char*)h_lds + 4 * 256 + t * 8) = 0ull;
    __syncthreads();

    const int arow  = lane & 15;
    const int abase = arow * 256;
    const int aswz  = (arow & 7) << 4;
    const int akoff = (lane >> 4) * 16;        // byte offset of 8 bf16 within k-tile

    for (int tt = 0; tt < TC; tt++) {
        // prefetch this step's input preacts (consumed after barrier 1)
        const size_t xr = ((size_t)(b0 + um) * TC + tt) * 512 + uch;
        float xv0 = xg[xr];
        float xv1 = xg[xr + 128];
        float xv2 = xg[xr + 256];
        float xv3 = xg[xr + 384];

        // A-fragments from swizzled h_lds
        bf16x8 Af[4];
#pragma unroll
        for (int kt = 0; kt < 4; kt++)
            Af[kt] = *(const bf16x8*)((const char*)h_lds + abase + ((kt * 64 + akoff) ^ aswz));

        // 4 gate-type N-tiles x K=128 accumulation chain
        f32x4 acc[4];
#pragma unroll
        for (int q = 0; q < 4; q++) {
            f32x4 a = {0.f, 0.f, 0.f, 0.f};
#pragma unroll
            for (int kt = 0; kt < 4; kt++)
                a = __builtin_amdgcn_mfma_f32_16x16x32_bf16(Af[kt], Wf[q][kt], a, 0, 0, 0);
            acc[q] = a;
        }

        // lanes 0-15 hold the 4 real rows in regs 0-3 -> scatter to pre[q][m][ch]
        if ((lane >> 4) == 0) {
            const int chw = w * 16 + arow;
#pragma unroll
            for (int q = 0; q < 4; q++)
#pragma unroll
                for (int r = 0; r < 4; r++)
                    pre[q * 512 + r * 128 + chw] = acc[q][r];
        }
        __syncthreads();

        // per-thread gate-quad update (1 quad/thread)
        float pi = pre[0 * 512 + um * 128 + uch] + xv0;
        float pf = pre[1 * 512 + um * 128 + uch] + xv1;
        float pg = pre[2 * 512 + um * 128 + uch] + xv2;
        float po = pre[3 * 512 + um * 128 + uch] + xv3;
        float iv = sigm(pi), fv = sigm(pf), gv = tanhfast(pg), ov = sigm(po);
        c_reg = fv * c_reg + iv * gv;
        float hv = ov * tanhfast(c_reg);
        h_keep = hv;
        *(short*)((char*)h_lds + um * 256 + ((uch * 2) ^ (um << 4))) = f2bf(hv);
        if (WRITE_H)
            hout[((size_t)(b0 + um) * TC + tt) * 128 + uch] = hv;
        __syncthreads();
    }

    hs[(size_t)(b0 + um) * 128 + uch] = h_keep;
    cs[(size_t)(b0 + um) * 128 + uch] = c_reg;
}

// ---------------- head ---------------------------------------------------------------
__global__ __launch_bounds__(256, 2)
void head_k(const float* __restrict__ h1s, const float* __restrict__ W1,
            const float* __restrict__ b1, const float* __restrict__ W2,
            const float* __restrict__ b2, float* __restrict__ out)
{
    __shared__ float hrow[128];
    __shared__ float y1[256];
    const int b = blockIdx.x;
    const int tid = threadIdx.x;
    if (tid < 128) hrow[tid] = h1s[(size_t)b * 128 + tid];
    __syncthreads();
    {
        float acc = b1[tid];
        const float4* wp = (const float4*)(W1 + (size_t)tid * 128);
        const float4* hp = (const float4*)hrow;
#pragma unroll 8
        for (int q = 0; q < 32; q++) {
            float4 wv = wp[q]; float4 hv = hp[q];
            acc += wv.x * hv.x + wv.y * hv.y + wv.z * hv.z + wv.w * hv.w;
        }
        y1[tid] = celu1(acc);
    }
    __syncthreads();
    if (tid < 32) {
        float acc = b2[tid];
        const float4* wp = (const float4*)(W2 + (size_t)tid * 256);
        const float4* yp = (const float4*)y1;
#pragma unroll 8
        for (int q = 0; q < 64; q++) {
            float4 wv = wp[q]; float4 yv = yp[q];
            acc += wv.x * yv.x + wv.y * yv.y + wv.z * yv.z + wv.w * yv.w;
        }
        out[(size_t)b * 32 + tid] = celu1(acc);
    }
}

extern "C" void kernel_launch(void* const* d_in, const int* in_sizes, int n_in,
                              void* d_out, int out_size, void* d_ws, size_t ws_size,
                              hipStream_t stream)
{
    const float* x    = (const float*)d_in[0];
    const float* Wih0 = (const float*)d_in[1];
    const float* Whh0 = (const float*)d_in[2];
    const float* bih0 = (const float*)d_in[3];
    const float* bhh0 = (const float*)d_in[4];
    const float* Wih1 = (const float*)d_in[5];
    const float* Whh1 = (const float*)d_in[6];
    const float* bih1 = (const float*)d_in[7];
    const float* bhh1 = (const float*)d_in[8];
    const float* W1   = (const float*)d_in[9];
    const float* b1   = (const float*)d_in[10];
    const float* W2   = (const float*)d_in[11];
    const float* b2   = (const float*)d_in[12];
    float* out = (float*)d_out;

    int TC = 128;
    while (TC > 8) {
        size_t need = (size_t)TC * (512ull * 512 + 512ull * 128) * 4 + 4ull * 512 * 128 * 4;
        if (need <= ws_size) break;
        TC >>= 1;
    }

    float* xg  = (float*)d_ws;
    float* h0c = xg + (size_t)512 * TC * 512;
    float* st  = h0c + (size_t)512 * TC * 128;
    float* h0s = st;
    float* c0s = st + 512 * 128;
    float* h1s = st + 2 * 512 * 128;
    float* c1s = st + 3 * 512 * 128;

    hipMemsetAsync(st, 0, (size_t)4 * 512 * 128 * 4, stream);
    hipMemsetAsync(out + 16384, 0, (size_t)131072 * 4, stream);   // hidden_init

    const int NC = 1024 / TC;
    dim3 ggrid((unsigned)(512 * TC / 64), 8);
    for (int c = 0; c < NC; c++) {
        int t0 = c * TC;
        gemm_in<32,  true ><<<ggrid, 256, 0, stream>>>(x,   Wih0, bih0, bhh0, xg, t0, TC);
        lstm_scan<1><<<128, 512, 0, stream>>>(xg, Whh0, h0s, c0s, h0c, TC);
        gemm_in<128, false><<<ggrid, 256, 0, stream>>>(h0c, Wih1, bih1, bhh1, xg, t0, TC);
        lstm_scan<0><<<128, 512, 0, stream>>>(xg, Whh1, h1s, c1s, nullptr, TC);
    }
    head_k<<<512, 256, 0, stream>>>(h1s, W1, b1, W2, b2, out);
}

// Round 4
// 1642.590 us; speedup vs baseline: 3.1261x; 2.0599x over previous
//
#include <hip/hip_runtime.h>
#include <hip/hip_bf16.h>

// LSTMNet: B=512, T=1024, IN=32, H=128 (gates G=512), 2 layers, head 128->256->32 (CELU).
// Round 3:
//  - gemm_mfma: bf16 MFMA input-projection GEMM (128x128 tile, XOR-swizzled LDS,
//    ds_read_b128 <=2-way). Write-bound (131 MB fp32 out/dispatch) -> single-stage.
//  - x, Wih*, Whh* pre-converted to bf16 (one-time kernels); h0c stored bf16 by the
//    scan (same bits the scan's own MFMA uses -> no added error, half the traffic).
//  - lstm_scan_dual: L0-scan(chunk c) || L1-scan(chunk c-1) in one 256-block kernel
//    (the scan is latency-bound at 128 blocks = half the CUs; fusion fills the machine).
//    Pipeline: G0(0); S0(0); { G1(c-1); G0(c); F(c) } c=1..NC-1; G1(NC-1); S1; head.

#define DEV __device__ __forceinline__

typedef float f32x4 __attribute__((ext_vector_type(4)));
typedef short bf16x8 __attribute__((ext_vector_type(8)));
typedef unsigned short ushort_t;

DEV float sigm(float x) { return 1.f / (1.f + __expf(-x)); }
DEV float tanhfast(float x) { float e = __expf(2.f * x); return (e - 1.f) / (e + 1.f); }
DEV float celu1(float x) { return x > 0.f ? x : (__expf(x) - 1.f); }

DEV short f2bf(float f) {
    __hip_bfloat16 h = __float2bfloat16(f);   // RNE
    return *reinterpret_cast<short*>(&h);
}

// ---------------- f32 -> bf16 convert (one-time) ------------------------------------
__global__ __launch_bounds__(256)
void cvt_bf16(const float* __restrict__ in, ushort_t* __restrict__ out, int n8)
{
    int i = blockIdx.x * 256 + threadIdx.x;
    if (i >= n8) return;
    const float4* p = (const float4*)(in + (size_t)i * 8);
    float4 a = p[0], b = p[1];
    bf16x8 v;
    v[0] = f2bf(a.x); v[1] = f2bf(a.y); v[2] = f2bf(a.z); v[3] = f2bf(a.w);
    v[4] = f2bf(b.x); v[5] = f2bf(b.y); v[6] = f2bf(b.z); v[7] = f2bf(b.w);
    *(bf16x8*)(out + (size_t)i * 8) = v;
}

// ---------------- bf16 MFMA input-projection GEMM -----------------------------------
// C[r][g] = sum_k A[r][k]*W[g][k] + bA[g] + bB[g]; C fp32 [*, 512]. A,W bf16.
// Tile 128(M) x 128(N) x full-K. 256 threads (4 waves); wave w: rows w*32..w*32+31.
// XMAP: A = xbf (B,1024,32) row r -> (b = r/TC, t = t0 + r%TC).
template<int K, bool XMAP>
__global__ __launch_bounds__(256, 2)
void gemm_mfma(const ushort_t* __restrict__ A, const ushort_t* __restrict__ Wg,
               const float* __restrict__ bA, const float* __restrict__ bB,
               float* __restrict__ C, int t0, int TC)
{
    constexpr int SWB = K * 2;                // row bytes in LDS
    constexpr int SM  = (K == 32) ? 3 : 7;    // swizzle mask (keep XOR inside the row)
    __shared__ char As[128 * SWB];
    __shared__ char Ws[128 * SWB];

    const int tid = threadIdx.x;
    const int r0 = blockIdx.x * 128;
    const int g0 = blockIdx.y * 128;
    const int lane = tid & 63, w = tid >> 6;
    const int lr = lane & 15, kg = lane >> 4;

    // stage A & W tiles: global 16B loads -> swizzled ds_write_b128
    constexpr int UPR = SWB / 16;             // 16B units per row
    constexpr int NIT = 128 * UPR / 256;
#pragma unroll
    for (int e = 0; e < NIT; e++) {
        int idx = tid + e * 256;
        int row = idx / UPR;
        int kb  = (idx - row * UPR) * 16;
        int dst = row * SWB + (kb ^ ((row & SM) << 4));
        size_t src;
        int r = r0 + row;
        if (XMAP) {
            int b = r / TC, tt = r - b * TC;
            src = ((size_t)b * 1024 + (size_t)(t0 + tt)) * 32 + (size_t)(kb >> 1);
        } else {
            src = (size_t)r * K + (size_t)(kb >> 1);
        }
        *(bf16x8*)(As + dst) = *(const bf16x8*)(A + src);
        *(bf16x8*)(Ws + dst) = *(const bf16x8*)(Wg + (size_t)(g0 + row) * K + (size_t)(kb >> 1));
    }
    __syncthreads();

    f32x4 acc[2][8];
#pragma unroll
    for (int mi = 0; mi < 2; mi++)
#pragma unroll
        for (int n = 0; n < 8; n++) acc[mi][n] = (f32x4){0.f, 0.f, 0.f, 0.f};

    const int m0 = w * 32;
#pragma unroll
    for (int ks = 0; ks < K / 32; ks++) {
        const int kb = ks * 64 + kg * 16;
        const int ra0 = m0 + lr, ra1 = m0 + 16 + lr;
        bf16x8 a0 = *(const bf16x8*)(As + ra0 * SWB + (kb ^ ((ra0 & SM) << 4)));
        bf16x8 a1 = *(const bf16x8*)(As + ra1 * SWB + (kb ^ ((ra1 & SM) << 4)));
#pragma unroll
        for (int n = 0; n < 8; n++) {
            int wr = n * 16 + lr;
            bf16x8 bw = *(const bf16x8*)(Ws + wr * SWB + (kb ^ ((wr & SM) << 4)));
            acc[0][n] = __builtin_amdgcn_mfma_f32_16x16x32_bf16(a0, bw, acc[0][n], 0, 0, 0);
            acc[1][n] = __builtin_amdgcn_mfma_f32_16x16x32_bf16(a1, bw, acc[1][n], 0, 0, 0);
        }
    }

    // epilogue: D col = lane&15 (gate), row = kg*4 + reg (within 16-row M-tile)
#pragma unroll
    for (int n = 0; n < 8; n++) {
        int g = g0 + n * 16 + lr;
        float bias = bA[g] + bB[g];
#pragma unroll
        for (int mi = 0; mi < 2; mi++) {
            int rrow = r0 + m0 + mi * 16 + kg * 4;
#pragma unroll
            for (int rr = 0; rr < 4; rr++)
                C[(size_t)(rrow + rr) * 512 + g] = acc[mi][n][rr] + bias;
        }
    }
}

// ---------------- MFMA LSTM scan body ------------------------------------------------
// Block: 4 batch rows, 512 threads (8 waves). Wave w owns channels w*16..w*16+15 for
// all 4 gate types. Whh bf16 B-frags (64 VGPR) loaded once, pinned. h bf16 in LDS,
// XOR-swizzled. Preacts via LDS; 1 gate-quad per thread. 2 barriers/step.
template<int WRITE_H>
DEV void scan_body(const float* __restrict__ xg, const ushort_t* __restrict__ whh,
                   float* __restrict__ hs, float* __restrict__ cs,
                   ushort_t* __restrict__ hout, int TC, int blk)
{
    __shared__ short h_lds[16 * 128];          // bf16 bits, swizzled ^((m&7)<<4)
    __shared__ float pre[4 * 4 * 128];         // [q][m][ch]

    const int t    = threadIdx.x;
    const int lane = t & 63;
    const int w    = t >> 6;
    const int b0   = blk * 4;
    const int um   = t >> 7;
    const int uch  = t & 127;
    const int lr   = lane & 15, kg = lane >> 4;

    // Whh bf16 -> B-fragments (once)
    bf16x8 Wf[4][4];
#pragma unroll
    for (int q = 0; q < 4; q++)
#pragma unroll
        for (int kt = 0; kt < 4; kt++)
            Wf[q][kt] = *(const bf16x8*)(whh + (size_t)(q * 128 + w * 16 + lr) * 128
                                              + kt * 32 + kg * 8);
    asm volatile("" : "+v"(Wf[0][0]), "+v"(Wf[0][1]), "+v"(Wf[0][2]), "+v"(Wf[0][3]),
                      "+v"(Wf[1][0]), "+v"(Wf[1][1]), "+v"(Wf[1][2]), "+v"(Wf[1][3]),
                      "+v"(Wf[2][0]), "+v"(Wf[2][1]), "+v"(Wf[2][2]), "+v"(Wf[2][3]),
                      "+v"(Wf[3][0]), "+v"(Wf[3][1]), "+v"(Wf[3][2]), "+v"(Wf[3][3]));

    float c_reg  = cs[(size_t)(b0 + um) * 128 + uch];
    float h_keep = hs[(size_t)(b0 + um) * 128 + uch];
    *(short*)((char*)h_lds + um * 256 + ((uch * 2) ^ (um << 4))) = f2bf(h_keep);
    if (t < 384)   // zero rows 4..15 (A-tile padding; swizzle is a bijection per row)
        *(unsigned long long*)((char*)h_lds + 4 * 256 + t * 8) = 0ull;
    __syncthreads();

    const int abase = lr * 256;
    const int aswz  = (lr & 7) << 4;
    const int akoff = kg * 16;

    for (int tt = 0; tt < TC; tt++) {
        const size_t xr = ((size_t)(b0 + um) * TC + tt) * 512 + uch;
        float xv0 = xg[xr];
        float xv1 = xg[xr + 128];
        float xv2 = xg[xr + 256];
        float xv3 = xg[xr + 384];

        bf16x8 Af[4];
#pragma unroll
        for (int kt = 0; kt < 4; kt++)
            Af[kt] = *(const bf16x8*)((const char*)h_lds + abase + ((kt * 64 + akoff) ^ aswz));

        f32x4 acc[4];
#pragma unroll
        for (int q = 0; q < 4; q++) {
            f32x4 a = {0.f, 0.f, 0.f, 0.f};
#pragma unroll
            for (int kt = 0; kt < 4; kt++)
                a = __builtin_amdgcn_mfma_f32_16x16x32_bf16(Af[kt], Wf[q][kt], a, 0, 0, 0);
            acc[q] = a;
        }

        if (kg == 0) {
            const int chw = w * 16 + lr;
#pragma unroll
            for (int q = 0; q < 4; q++)
#pragma unroll
                for (int r = 0; r < 4; r++)
                    pre[q * 512 + r * 128 + chw] = acc[q][r];
        }
        __syncthreads();

        float pi = pre[0 * 512 + um * 128 + uch] + xv0;
        float pf = pre[1 * 512 + um * 128 + uch] + xv1;
        float pg = pre[2 * 512 + um * 128 + uch] + xv2;
        float po = pre[3 * 512 + um * 128 + uch] + xv3;
        float iv = sigm(pi), fv = sigm(pf), gv = tanhfast(pg), ov = sigm(po);
        c_reg = fv * c_reg + iv * gv;
        float hv = ov * tanhfast(c_reg);
        h_keep = hv;
        short hb = f2bf(hv);
        *(short*)((char*)h_lds + um * 256 + ((uch * 2) ^ (um << 4))) = hb;
        if (WRITE_H)
            hout[((size_t)(b0 + um) * TC + tt) * 128 + uch] = (ushort_t)hb;
        __syncthreads();
    }

    hs[(size_t)(b0 + um) * 128 + uch] = h_keep;
    cs[(size_t)(b0 + um) * 128 + uch] = c_reg;
}

template<int WRITE_H>
__global__ __launch_bounds__(512, 2)
void lstm_scan(const float* __restrict__ xg, const ushort_t* __restrict__ whh,
               float* __restrict__ hs, float* __restrict__ cs,
               ushort_t* __restrict__ hout, int TC)
{
    scan_body<WRITE_H>(xg, whh, hs, cs, hout, TC, blockIdx.x);
}

// blocks 0-127: layer-0 scan chunk c (writes h0c bf16); 128-255: layer-1 scan chunk c-1
__global__ __launch_bounds__(512, 2)
void lstm_scan_dual(const float* __restrict__ xg0, const ushort_t* __restrict__ whh0,
                    float* __restrict__ h0s, float* __restrict__ c0s,
                    ushort_t* __restrict__ hout,
                    const float* __restrict__ xg1, const ushort_t* __restrict__ whh1,
                    float* __restrict__ h1s, float* __restrict__ c1s, int TC)
{
    if (blockIdx.x < 128)
        scan_body<1>(xg0, whh0, h0s, c0s, hout, TC, blockIdx.x);
    else
        scan_body<0>(xg1, whh1, h1s, c1s, nullptr, TC, blockIdx.x - 128);
}

// ---------------- head ---------------------------------------------------------------
__global__ __launch_bounds__(256, 2)
void head_k(const float* __restrict__ h1s, const float* __restrict__ W1,
            const float* __restrict__ b1, const float* __restrict__ W2,
            const float* __restrict__ b2, float* __restrict__ out)
{
    __shared__ float hrow[128];
    __shared__ float y1[256];
    const int b = blockIdx.x;
    const int tid = threadIdx.x;
    if (tid < 128) hrow[tid] = h1s[(size_t)b * 128 + tid];
    __syncthreads();
    {
        float acc = b1[tid];
        const float4* wp = (const float4*)(W1 + (size_t)tid * 128);
        const float4* hp = (const float4*)hrow;
#pragma unroll 8
        for (int q = 0; q < 32; q++) {
            float4 wv = wp[q]; float4 hv = hp[q];
            acc += wv.x * hv.x + wv.y * hv.y + wv.z * hv.z + wv.w * hv.w;
        }
        y1[tid] = celu1(acc);
    }
    __syncthreads();
    if (tid < 32) {
        float acc = b2[tid];
        const float4* wp = (const float4*)(W2 + (size_t)tid * 256);
        const float4* yp = (const float4*)y1;
#pragma unroll 8
        for (int q = 0; q < 64; q++) {
            float4 wv = wp[q]; float4 yv = yp[q];
            acc += wv.x * yv.x + wv.y * yv.y + wv.z * yv.z + wv.w * yv.w;
        }
        out[(size_t)b * 32 + tid] = celu1(acc);
    }
}

extern "C" void kernel_launch(void* const* d_in, const int* in_sizes, int n_in,
                              void* d_out, int out_size, void* d_ws, size_t ws_size,
                              hipStream_t stream)
{
    const float* x    = (const float*)d_in[0];
    const float* Wih0 = (const float*)d_in[1];
    const float* Whh0 = (const float*)d_in[2];
    const float* bih0 = (const float*)d_in[3];
    const float* bhh0 = (const float*)d_in[4];
    const float* Wih1 = (const float*)d_in[5];
    const float* Whh1 = (const float*)d_in[6];
    const float* bih1 = (const float*)d_in[7];
    const float* bhh1 = (const float*)d_in[8];
    const float* W1   = (const float*)d_in[9];
    const float* b1   = (const float*)d_in[10];
    const float* W2   = (const float*)d_in[11];
    const float* b2   = (const float*)d_in[12];
    float* out = (float*)d_out;

    const size_t XN = 512ull * 1024 * 32;        // x elems
    // workspace: xg0, xg1 (fp32) | states (fp32) | h0c, xbf, wih0, wih1, whh0, whh1 (bf16)
    int TC = 128;
    while (TC > 8) {
        size_t need = (size_t)(2 * TC) * 512 * 512 * 4
                    + 4ull * 512 * 128 * 4
                    + ((size_t)512 * TC * 128 + XN + 512 * 32 + 3ull * 512 * 128) * 2;
        if (need <= ws_size) break;
        TC >>= 1;
    }

    float* xg0 = (float*)d_ws;
    float* xg1 = xg0 + (size_t)512 * TC * 512;
    float* st  = xg1 + (size_t)512 * TC * 512;
    float* h0s = st;
    float* c0s = st + 512 * 128;
    float* h1s = st + 2 * 512 * 128;
    float* c1s = st + 3 * 512 * 128;
    ushort_t* h0c  = (ushort_t*)(st + 4ull * 512 * 128);
    ushort_t* xbf  = h0c + (size_t)512 * TC * 128;
    ushort_t* wih0 = xbf + XN;
    ushort_t* wih1 = wih0 + 512 * 32;
    ushort_t* whh0 = wih1 + 512 * 128;
    ushort_t* whh1 = whh0 + 512 * 128;

    hipMemsetAsync(st, 0, (size_t)4 * 512 * 128 * 4, stream);
    hipMemsetAsync(out + 16384, 0, (size_t)131072 * 4, stream);   // hidden_init

    // one-time bf16 conversions
    cvt_bf16<<<(unsigned)(XN / 8 / 256), 256, 0, stream>>>(x, xbf, (int)(XN / 8));
    cvt_bf16<<<8,   256, 0, stream>>>(Wih0, wih0, 512 * 32 / 8);
    cvt_bf16<<<32,  256, 0, stream>>>(Wih1, wih1, 512 * 128 / 8);
    cvt_bf16<<<32,  256, 0, stream>>>(Whh0, whh0, 512 * 128 / 8);
    cvt_bf16<<<32,  256, 0, stream>>>(Whh1, whh1, 512 * 128 / 8);

    const int NC = 1024 / TC;
    dim3 ggrid((unsigned)(512 * TC / 128), 4);

    gemm_mfma<32, true ><<<ggrid, 256, 0, stream>>>(xbf, wih0, bih0, bhh0, xg0, 0, TC);
    lstm_scan<1><<<128, 512, 0, stream>>>(xg0, whh0, h0s, c0s, h0c, TC);
    for (int c = 1; c < NC; c++) {
        gemm_mfma<128, false><<<ggrid, 256, 0, stream>>>(h0c, wih1, bih1, bhh1, xg1, 0, TC);
        gemm_mfma<32,  true ><<<ggrid, 256, 0, stream>>>(xbf, wih0, bih0, bhh0, xg0, c * TC, TC);
        lstm_scan_dual<<<256, 512, 0, stream>>>(xg0, whh0, h0s, c0s, h0c,
                                                xg1, whh1, h1s, c1s, TC);
    }
    gemm_mfma<128, false><<<ggrid, 256, 0, stream>>>(h0c, wih1, bih1, bhh1, xg1, 0, TC);
    lstm_scan<0><<<128, 512, 0, stream>>>(xg1, whh1, h1s, c1s, nullptr, TC);

    head_k<<<512, 256, 0, stream>>>(h1s, W1, b1, W2, b2, out);
}